// Round 3
// baseline (536.797 us; speedup 1.0000x reference)
//
#include <hip/hip_runtime.h>
#include <hip/hip_bf16.h>
#include <math.h>

#define BATCH 512
#define EMBED 512
#define NCLS  100000
#define STRIPS 3125        // 100000 / 32, exact
#define NCG 64             // column groups

typedef __attribute__((ext_vector_type(4)))  float f32x4;
typedef __attribute__((ext_vector_type(16))) float f32x16;
typedef __attribute__((ext_vector_type(8)))  __bf16 bf16x8;
typedef __attribute__((ext_vector_type(4)))  unsigned int u32x4;

__device__ __forceinline__ unsigned short f2bf(float f) {
  unsigned int u = __builtin_bit_cast(unsigned int, f);
  u += 0x7fffu + ((u >> 16) & 1u);   // RNE
  return (unsigned short)(u >> 16);
}

constexpr float kCOS_M = 0.8775825618903728f;   // cos(0.5)
constexpr float kSIN_M = 0.4794255386042030f;   // sin(0.5)
constexpr float kTHR   = -0.8775825618903728f;  // cos(pi-0.5)
constexpr float kMM    = 0.2397127693021015f;   // sin(pi-0.5)*0.5

// ---------------- K1: normalize embeddings -> bf16 ----------------
__global__ void knorm_e(const float* __restrict__ E, unsigned short* __restrict__ En) {
  int row = blockIdx.x;
  int l = threadIdx.x;  // 64 lanes, one wave per row
  const float4* src = (const float4*)(E + row * EMBED);
  float4 a = src[l];
  float4 b = src[l + 64];
  float ss = a.x*a.x + a.y*a.y + a.z*a.z + a.w*a.w
           + b.x*b.x + b.y*b.y + b.z*b.z + b.w*b.w;
#pragma unroll
  for (int d = 1; d < 64; d <<= 1) ss += __shfl_xor(ss, d);
  float rn = 1.0f / fmaxf(sqrtf(ss), 1e-12f);
  ushort4 o;
  o.x = f2bf(a.x * rn); o.y = f2bf(a.y * rn); o.z = f2bf(a.z * rn); o.w = f2bf(a.w * rn);
  ((ushort4*)(En + row * EMBED))[l] = o;
  o.x = f2bf(b.x * rn); o.y = f2bf(b.y * rn); o.z = f2bf(b.z * rn); o.w = f2bf(b.w * rn);
  ((ushort4*)(En + row * EMBED))[l + 64] = o;
}

// ---------------- K2: label-column cosine + margin (512 rows) ----------------
__global__ void klabel(const unsigned short* __restrict__ En, const float* __restrict__ W,
                       const int* __restrict__ labels,
                       float* __restrict__ lcos, float* __restrict__ lphi)
{
  int r = blockIdx.x * 8 + (threadIdx.x >> 6);
  int l = threadIdx.x & 63;
  int lbl = labels[r];
  const float* wr = W + (size_t)lbl * EMBED + l * 8;
  f32x4 a = *(const f32x4*)(wr);
  f32x4 b = *(const f32x4*)(wr + 4);
  const unsigned short* er = En + r * EMBED + l * 8;
  float wv[8] = {a.x, a.y, a.z, a.w, b.x, b.y, b.z, b.w};
  float dot = 0.f, ssq = 0.f;
#pragma unroll
  for (int k = 0; k < 8; ++k) {
    unsigned int u = (unsigned int)er[k] << 16;
    float e = __builtin_bit_cast(float, u);
    dot = fmaf(e, wv[k], dot);
    ssq = fmaf(wv[k], wv[k], ssq);
  }
#pragma unroll
  for (int d = 1; d < 64; d <<= 1) { dot += __shfl_xor(dot, d); ssq += __shfl_xor(ssq, d); }
  float cosv = dot / fmaxf(sqrtf(ssq), 1e-12f);
  float cc = fminf(fmaxf(cosv, -1.f), 1.f);
  float sine = sqrtf(fmaxf(1.f - cc * cc, 0.f));
  float phi = (cosv > kTHR) ? (cosv * kCOS_M - sine * kSIN_M) : (cosv - kMM);
  if (l == 0) { lcos[r] = 64.f * cosv; lphi[r] = 64.f * phi; }
}

// ---------------- K3: main fused GEMM + fixed-max expsum ----------------
// 256 blocks, 1/CU. Block = 8 waves. A-panel (128 rows x 512 K bf16 = 128KB)
// staged once in LDS; each wave free-runs over 32-col strips, B streamed
// global->reg with double-buffered 4-kstep groups. No per-K barriers.
__global__ __launch_bounds__(512, 2) void kmain(
    const unsigned short* __restrict__ En, const float* __restrict__ W,
    float* __restrict__ psum)
{
  __shared__ unsigned short Asm[128 * EMBED];   // 128KB
  __shared__ float smemS[8 * 128];
  char* Ab = (char*)&Asm[0];

  int bid = blockIdx.x;
  int xcd = bid & 7;
  int idx = bid >> 3;
  int panel = idx & 3;               // 4 panels of same cg -> same XCD
  int cg = xcd + 8 * (idx >> 2);     // 0..63

  int tid = threadIdx.x;
  int w = tid >> 6, l = tid & 63;
  int cl = l & 31, kh = l >> 5;

  // ---- stage A panel (swizzled: 16B slot s of row r holds logical s^(r&15)) ----
#pragma unroll
  for (int i = 0; i < 16; ++i) {
    int q = i * 512 + tid;
    int rl = q >> 6, s = q & 63;
    u32x4 v = *(const u32x4*)(En + (panel * 128 + rl) * EMBED + s * 8);
    *(u32x4*)(Ab + rl * 1024 + ((s ^ (rl & 15)) << 4)) = v;
  }
  __syncthreads();

  f32x16 sacc[4];
#pragma unroll
  for (int rt = 0; rt < 4; ++rt)
#pragma unroll
    for (int e = 0; e < 16; ++e) sacc[rt][e] = 0.f;

  float ssq = 0.f;
  f32x16 acc[4];
  f32x4 bva[4][2], bvb[4][2];

  auto loadG = [&](f32x4 (&buf)[4][2], const float* wp, int gbase) {
#pragma unroll
    for (int t = 0; t < 4; ++t) {
      buf[t][0] = *(const f32x4*)(wp + (gbase + t) * 16);
      buf[t][1] = *(const f32x4*)(wp + (gbase + t) * 16 + 4);
    }
  };
  auto compG = [&](f32x4 (&buf)[4][2], int gbase) {
#pragma unroll
    for (int t = 0; t < 4; ++t) {
      int K = gbase + t;
      f32x4 a = buf[t][0], b = buf[t][1];
      ssq += a.x*a.x + a.y*a.y + a.z*a.z + a.w*a.w
           + b.x*b.x + b.y*b.y + b.z*b.z + b.w*b.w;
      unsigned int ux = __builtin_bit_cast(unsigned int, a.x) + 0x8000u;
      unsigned int uy = __builtin_bit_cast(unsigned int, a.y) + 0x8000u;
      unsigned int uz = __builtin_bit_cast(unsigned int, a.z) + 0x8000u;
      unsigned int uw = __builtin_bit_cast(unsigned int, a.w) + 0x8000u;
      unsigned int vx = __builtin_bit_cast(unsigned int, b.x) + 0x8000u;
      unsigned int vy = __builtin_bit_cast(unsigned int, b.y) + 0x8000u;
      unsigned int vz = __builtin_bit_cast(unsigned int, b.z) + 0x8000u;
      unsigned int vw = __builtin_bit_cast(unsigned int, b.w) + 0x8000u;
      u32x4 pk;
      pk.x = __builtin_amdgcn_perm(uy, ux, 0x07060302u);
      pk.y = __builtin_amdgcn_perm(uw, uz, 0x07060302u);
      pk.z = __builtin_amdgcn_perm(vy, vx, 0x07060302u);
      pk.w = __builtin_amdgcn_perm(vw, vz, 0x07060302u);
      bf16x8 bfr = __builtin_bit_cast(bf16x8, pk);
#pragma unroll
      for (int rt = 0; rt < 4; ++rt) {
        const bf16x8 af = *(const bf16x8*)(Ab + (rt * 32 + cl) * 1024 +
                                           (((K * 2 + kh) ^ (cl & 15)) << 4));
        acc[rt] = __builtin_amdgcn_mfma_f32_32x32x16_bf16(af, bfr, acc[rt], 0, 0, 0);
      }
    }
  };

  int cnt = (STRIPS - cg + 63) >> 6;   // 49 (cg<=52) or 48
  int j = w;
  bool have = (j < cnt);
  const float* wp = W + (size_t)((cg + 64 * j) * 32 + cl) * EMBED + kh * 8;
  if (have) loadG(bva, wp, 0);

  while (have) {
    int jn = j + 8;
    bool more = (jn < cnt);
    const float* wpn = more ? (W + (size_t)((cg + 64 * jn) * 32 + cl) * EMBED + kh * 8) : wp;

    ssq = 0.f;
#pragma unroll
    for (int rt = 0; rt < 4; ++rt)
#pragma unroll
      for (int e = 0; e < 16; ++e) acc[rt][e] = 0.f;

#pragma unroll
    for (int g = 0; g < 8; ++g) {
      if ((g & 1) == 0) {
        if (g < 7) loadG(bvb, wp, (g + 1) * 4);
        compG(bva, g * 4);
      } else {
        if (g < 7) loadG(bva, wp, (g + 1) * 4);
        else       loadG(bva, wpn, 0);          // prefetch next strip's group 0
        compG(bvb, g * 4);
      }
    }

    // strip epilogue: per-col rnorm, fixed-max-64 exp accumulation
    float sst = ssq + __shfl_xor(ssq, 32);
    float rn64 = 64.0f / fmaxf(sqrtf(sst), 1e-12f);
#pragma unroll
    for (int rt = 0; rt < 4; ++rt)
#pragma unroll
      for (int e = 0; e < 16; ++e)
        sacc[rt][e] += __expf(fmaf(acc[rt][e], rn64, -64.0f));

    wp = wpn; j = jn; have = more;
  }

  // ---- wave fold: reduce over 32 col-lanes, write per-row sums ----
#pragma unroll
  for (int rt = 0; rt < 4; ++rt)
#pragma unroll
    for (int e = 0; e < 16; ++e) {
      float v = sacc[rt][e];
      v += __shfl_xor(v, 1); v += __shfl_xor(v, 2); v += __shfl_xor(v, 4);
      v += __shfl_xor(v, 8); v += __shfl_xor(v, 16);
      sacc[rt][e] = v;
    }
  if (cl == 0) {
#pragma unroll
    for (int rt = 0; rt < 4; ++rt)
#pragma unroll
      for (int e = 0; e < 16; ++e) {
        int row = rt * 32 + (e & 3) + 8 * (e >> 2) + 4 * kh;
        smemS[w * 128 + row] = sacc[rt][e];
      }
  }
  __syncthreads();
  if (tid < 128) {
    float t = 0.f;
#pragma unroll
    for (int q = 0; q < 8; ++q) t += smemS[q * 128 + tid];
    psum[bid * 128 + tid] = t;
  }
}

// ---------------- K4: combine + label adjust + NLL mean ----------------
__global__ void kfinal(const float* __restrict__ psum, const float* __restrict__ lcos,
                       const float* __restrict__ lphi, float* __restrict__ out)
{
  int tid = threadIdx.x;      // 512 = one thread per batch row
  int p = tid >> 7, rl = tid & 127;
  float S = 0.f;
#pragma unroll
  for (int cg = 0; cg < 64; ++cg) {
    int b = (cg & 7) + 8 * (p + 4 * (cg >> 3));
    S += psum[b * 128 + rl];
  }
  float lc = lcos[tid], lp = lphi[tid];
  S = S - __expf(lc - 64.f) + __expf(lp - 64.f);
  float nll = 64.f + __logf(S) - lp;
#pragma unroll
  for (int d = 1; d < 64; d <<= 1) nll += __shfl_xor(nll, d);
  __shared__ float sm[8];
  if ((tid & 63) == 0) sm[tid >> 6] = nll;
  __syncthreads();
  if (tid == 0) {
    float t = 0.f;
    for (int k = 0; k < 8; ++k) t += sm[k];
    out[0] = t * (1.0f / 512.0f);
  }
}

extern "C" void kernel_launch(void* const* d_in, const int* in_sizes, int n_in,
                              void* d_out, int out_size, void* d_ws, size_t ws_size,
                              hipStream_t stream)
{
  const float* E      = (const float*)d_in[0];
  const int*   labels = (const int*)d_in[1];
  const float* W      = (const float*)d_in[2];
  float* out = (float*)d_out;

  char* ws = (char*)d_ws;
  unsigned short* En = (unsigned short*)ws;            // 512*512*2 = 524288 B
  float* psum = (float*)(ws + 524288);                 // 256*128*4 = 131072 B
  float* lcos = (float*)(ws + 524288 + 131072);        // 2048 B
  float* lphi = lcos + BATCH;                          // 2048 B

  knorm_e<<<BATCH, 64, 0, stream>>>(E, En);
  klabel <<<64, 512, 0, stream>>>(En, W, labels, lcos, lphi);
  kmain  <<<256, 512, 0, stream>>>(En, W, psum);
  kfinal <<<1, 512, 0, stream>>>(psum, lcos, lphi, out);
}

// Round 4
// 160.613 us; speedup vs baseline: 3.3422x; 3.3422x over previous
//
#include <hip/hip_runtime.h>
#include <hip/hip_bf16.h>
#include <math.h>

#define BATCH 512
#define EMBED 512
#define NCLS  100000
#define NTILE 1563           // ceil(100000/64); last tile has 32 pad classes
#define GRID  256
#define NRED  32             // kred1 blocks; 32*49 >= 1563

typedef __attribute__((ext_vector_type(4)))  float f32x4;
typedef __attribute__((ext_vector_type(16))) float f32x16;
typedef __attribute__((ext_vector_type(8)))  __bf16 bf16x8;
typedef __attribute__((ext_vector_type(4)))  unsigned int u32x4;

__device__ __forceinline__ unsigned int rbf(unsigned int x) {
  return x + 0x7fffu + ((x >> 16) & 1u);   // RNE to bf16 (in high 16)
}
__device__ __forceinline__ unsigned short f2bf(float f) {
  return (unsigned short)(rbf(__builtin_bit_cast(unsigned int, f)) >> 16);
}

constexpr float kCOS_M = 0.8775825618903728f;   // cos(0.5)
constexpr float kSIN_M = 0.4794255386042030f;   // sin(0.5)
constexpr float kTHR   = -0.8775825618903728f;  // cos(pi-0.5)
constexpr float kMM    = 0.2397127693021015f;   // sin(pi-0.5)*0.5

// ---------------- K1: normalize embeddings -> bf16 ----------------
__global__ void knorm_e(const float* __restrict__ E, unsigned short* __restrict__ En) {
  int row = blockIdx.x;
  int l = threadIdx.x;  // 64 lanes, one wave per row
  const float4* src = (const float4*)(E + row * EMBED);
  float4 a = src[l];
  float4 b = src[l + 64];
  float ss = a.x*a.x + a.y*a.y + a.z*a.z + a.w*a.w
           + b.x*b.x + b.y*b.y + b.z*b.z + b.w*b.w;
#pragma unroll
  for (int d = 1; d < 64; d <<= 1) ss += __shfl_xor(ss, d);
  float rn = 1.0f / fmaxf(sqrtf(ss), 1e-12f);
  ushort4 o;
  o.x = f2bf(a.x * rn); o.y = f2bf(a.y * rn); o.z = f2bf(a.z * rn); o.w = f2bf(a.w * rn);
  ((ushort4*)(En + row * EMBED))[l] = o;
  o.x = f2bf(b.x * rn); o.y = f2bf(b.y * rn); o.z = f2bf(b.z * rn); o.w = f2bf(b.w * rn);
  ((ushort4*)(En + row * EMBED))[l + 64] = o;
}

// ---------------- K2: label-column cosine + margin (512 rows) ----------------
__global__ void klabel(const unsigned short* __restrict__ En, const float* __restrict__ W,
                       const int* __restrict__ labels,
                       float* __restrict__ lcos, float* __restrict__ lphi)
{
  int r = blockIdx.x * 8 + (threadIdx.x >> 6);
  int l = threadIdx.x & 63;
  int lbl = labels[r];
  const float* wr = W + (size_t)lbl * EMBED + l * 8;
  f32x4 a = *(const f32x4*)(wr);
  f32x4 b = *(const f32x4*)(wr + 4);
  const unsigned short* er = En + r * EMBED + l * 8;
  float wv[8] = {a.x, a.y, a.z, a.w, b.x, b.y, b.z, b.w};
  float dot = 0.f, ssq = 0.f;
#pragma unroll
  for (int k = 0; k < 8; ++k) {
    unsigned int u = (unsigned int)er[k] << 16;
    float e = __builtin_bit_cast(float, u);
    dot = fmaf(e, wv[k], dot);
    ssq = fmaf(wv[k], wv[k], ssq);
  }
#pragma unroll
  for (int d = 1; d < 64; d <<= 1) { dot += __shfl_xor(dot, d); ssq += __shfl_xor(ssq, d); }
  float cosv = dot / fmaxf(sqrtf(ssq), 1e-12f);
  float cc = fminf(fmaxf(cosv, -1.f), 1.f);
  float sine = sqrtf(fmaxf(1.f - cc * cc, 0.f));
  float phi = (cosv > kTHR) ? (cosv * kCOS_M - sine * kSIN_M) : (cosv - kMM);
  if (l == 0) { lcos[r] = 64.f * cosv; lphi[r] = 64.f * phi; }
}

// ---------------- K3: persistent fused GEMM + fixed-max expsum ----------------
// 256 blocks (1/CU), 512 threads (8 waves). Each block loops over 6-7
// class-tiles of 64 classes; BM=512 (whole batch), BK=64, KT=8 phases/tile.
// 2-barrier phase: loads for phase p+1 issued AFTER barrier2 of phase p,
// consumed in phase p+1 -> every drain waits on loads with a full phase of
// latency slack; ~80 KB/CU in flight -> HBM BW saturated. W read exactly once.
__global__ __launch_bounds__(512, 2) void kmain(
    const unsigned short* __restrict__ En, const float* __restrict__ W,
    float* __restrict__ psum)
{
  __shared__ unsigned short Abuf[2][BATCH * 64];  // 2 x 64 KB
  __shared__ unsigned short Bbuf[2][64 * 64];     // 2 x 8 KB
  __shared__ float rowsum[64];

  int b = blockIdx.x;
  int tid = threadIdx.x, w = tid >> 6, lane = tid & 63;
  int cl = lane & 31, hi = lane >> 5;
  int bcls = tid >> 3, bseg = tid & 7;   // B ownership: class (0..63), 8-float seg

  int ntiles = (b < 27) ? 7 : 6;         // 1563 = 6*256 + 27
  int nph = ntiles * 8;

  // A staging: global_load_lds, linear LDS dest (wave-uniform base), source
  // pre-swizzled so phys 16B-slot sp of row r holds logical slot sp^(r&7).
  auto stageA = [&](int buf, int kt) {
#pragma unroll
    for (int i = 0; i < 8; ++i) {
      int qb = i * 512 + w * 64;         // wave-uniform 16B-slot base
      int q = qb + lane;
      int row = q >> 3, sp = q & 7;
      int sl = sp ^ (row & 7);
      const unsigned short* src = En + row * EMBED + kt * 64 + sl * 8;
      __builtin_amdgcn_global_load_lds(
          (const __attribute__((address_space(1))) void*)src,
          (__attribute__((address_space(3))) void*)((char*)&Abuf[buf][0] + qb * 16),
          16, 0, 0);
    }
  };

  f32x4 bv0, bv1;
  bool bvalid = false;
  auto loadB = [&](int ct, int kt) {
    size_t cgl = (size_t)ct * 64 + bcls;
    bvalid = cgl < NCLS;
    const float* p = W + (bvalid ? cgl : (size_t)(NCLS - 1)) * EMBED + kt * 64 + bseg * 8;
    bv0 = *(const f32x4*)p;
    bv1 = *(const f32x4*)(p + 4);
  };

  float ssq = 0.f;
  auto writeB = [&](int buf) {
    f32x4 a = bv0, c = bv1;
    if (!bvalid) { a = (f32x4){0,0,0,0}; c = (f32x4){0,0,0,0}; }
    ssq += a.x*a.x + a.y*a.y + a.z*a.z + a.w*a.w
         + c.x*c.x + c.y*c.y + c.z*c.z + c.w*c.w;
    u32x4 pk;
    pk.x = __builtin_amdgcn_perm(rbf(__builtin_bit_cast(unsigned int, a.y)),
                                 rbf(__builtin_bit_cast(unsigned int, a.x)), 0x07060302u);
    pk.y = __builtin_amdgcn_perm(rbf(__builtin_bit_cast(unsigned int, a.w)),
                                 rbf(__builtin_bit_cast(unsigned int, a.z)), 0x07060302u);
    pk.z = __builtin_amdgcn_perm(rbf(__builtin_bit_cast(unsigned int, c.y)),
                                 rbf(__builtin_bit_cast(unsigned int, c.x)), 0x07060302u);
    pk.w = __builtin_amdgcn_perm(rbf(__builtin_bit_cast(unsigned int, c.w)),
                                 rbf(__builtin_bit_cast(unsigned int, c.z)), 0x07060302u);
    char* dst = (char*)&Bbuf[buf][0] + bcls * 128 + ((bseg ^ (bcls & 7)) << 4);
    *(u32x4*)dst = pk;
  };

  f32x16 acc[2][2];
#pragma unroll
  for (int mf = 0; mf < 2; ++mf)
#pragma unroll
    for (int nf = 0; nf < 2; ++nf)
#pragma unroll
      for (int e = 0; e < 16; ++e) acc[mf][nf][e] = 0.f;

  // prologue: issue tile(b) phase-0 loads
  stageA(0, 0);
  loadB(b, 0);

  int ct = b;
  for (int p = 0; p < nph; ++p) {
    int cur = p & 1;
    __syncthreads();                       // B1: drains glds(p) + B-loads(p)
    writeB(cur);                           // convert + ds_write Bbuf[cur]
    __syncthreads();                       // B2: tile-p LDS ready (nothing in vm queue)
    if (p + 1 < nph) {
      int pn = p + 1;
      stageA(cur ^ 1, pn & 7);             // issue next phase's A
      loadB(b + (pn >> 3) * GRID, pn & 7); // issue next phase's B
    }
#pragma unroll
    for (int kk = 0; kk < 4; ++kk) {
      int so = ((kk * 2 + hi) ^ (cl & 7)) << 4;
      bf16x8 a0 = *(const bf16x8*)((const char*)&Abuf[cur][0] + (w * 64 + cl) * 128 + so);
      bf16x8 a1 = *(const bf16x8*)((const char*)&Abuf[cur][0] + (w * 64 + 32 + cl) * 128 + so);
      bf16x8 b0 = *(const bf16x8*)((const char*)&Bbuf[cur][0] + cl * 128 + so);
      bf16x8 b1 = *(const bf16x8*)((const char*)&Bbuf[cur][0] + (32 + cl) * 128 + so);
      acc[0][0] = __builtin_amdgcn_mfma_f32_32x32x16_bf16(a0, b0, acc[0][0], 0, 0, 0);
      acc[0][1] = __builtin_amdgcn_mfma_f32_32x32x16_bf16(a0, b1, acc[0][1], 0, 0, 0);
      acc[1][0] = __builtin_amdgcn_mfma_f32_32x32x16_bf16(a1, b0, acc[1][0], 0, 0, 0);
      acc[1][1] = __builtin_amdgcn_mfma_f32_32x32x16_bf16(a1, b1, acc[1][1], 0, 0, 0);
    }
    if ((p & 7) == 7) {
      // ---- tile epilogue ----
      float sq = ssq;
      sq += __shfl_xor(sq, 1); sq += __shfl_xor(sq, 2); sq += __shfl_xor(sq, 4);
      if (bseg == 0) rowsum[bcls] = sq;
      ssq = 0.f;
      __syncthreads();
      float rn0 = 64.0f / fmaxf(sqrtf(rowsum[cl]), 1e-12f);
      float rn1 = 64.0f / fmaxf(sqrtf(rowsum[32 + cl]), 1e-12f);
#pragma unroll
      for (int mf = 0; mf < 2; ++mf) {
#pragma unroll
        for (int e = 0; e < 16; ++e) {
          float s = __expf(fmaf(acc[mf][0][e], rn0, -64.0f))
                  + __expf(fmaf(acc[mf][1][e], rn1, -64.0f));
          s += __shfl_xor(s, 1); s += __shfl_xor(s, 2); s += __shfl_xor(s, 4);
          s += __shfl_xor(s, 8); s += __shfl_xor(s, 16);
          if (cl == 0)
            psum[(size_t)ct * 512 + w * 64 + mf * 32 + (e & 3) + 8 * (e >> 2) + 4 * hi] = s;
          acc[mf][0][e] = 0.f; acc[mf][1][e] = 0.f;
        }
      }
      ct += GRID;
    }
  }
}

// ---------------- K4: reduce psum over tiles (stage 1) ----------------
__global__ void kred1(const float* __restrict__ psum, float* __restrict__ pp2) {
  int g = blockIdx.x, tid = threadIdx.x;   // 32 blocks x 512 threads
  int e0 = g * 49, e1 = e0 + 49;
  if (e1 > NTILE) e1 = NTILE;
  float s = 0.f;
  for (int c = e0; c < e1; ++c) s += psum[(size_t)c * 512 + tid];
  pp2[g * 512 + tid] = s;
}

// ---------------- K5: final combine + label adjust + NLL mean ----------------
__global__ void kfinal(const float* __restrict__ pp2, const float* __restrict__ lcos,
                       const float* __restrict__ lphi, float* __restrict__ out)
{
  int tid = threadIdx.x;      // 512 = one thread per batch row
  float S = 0.f;
#pragma unroll
  for (int g = 0; g < NRED; ++g) S += pp2[g * 512 + tid];
  float lc = lcos[tid], lp = lphi[tid];
  S = S - __expf(lc - 64.f) + __expf(lp - 64.f);
  float nll = 64.f + __logf(S) - lp;
#pragma unroll
  for (int d = 1; d < 64; d <<= 1) nll += __shfl_xor(nll, d);
  __shared__ float sm[8];
  if ((tid & 63) == 0) sm[tid >> 6] = nll;
  __syncthreads();
  if (tid == 0) {
    float t = 0.f;
    for (int k = 0; k < 8; ++k) t += sm[k];
    out[0] = t * (1.0f / 512.0f);
  }
}

extern "C" void kernel_launch(void* const* d_in, const int* in_sizes, int n_in,
                              void* d_out, int out_size, void* d_ws, size_t ws_size,
                              hipStream_t stream)
{
  const float* E      = (const float*)d_in[0];
  const int*   labels = (const int*)d_in[1];
  const float* W      = (const float*)d_in[2];
  float* out = (float*)d_out;

  char* ws = (char*)d_ws;
  unsigned short* En = (unsigned short*)ws;                 // 524288 B
  float* psum = (float*)(ws + 524288);                      // 1563*512*4 = 3201024 B
  float* pp2  = (float*)(ws + 524288 + 3201024);            // 32*512*4 = 65536 B
  float* lcos = (float*)(ws + 524288 + 3201024 + 65536);    // 2048 B
  float* lphi = lcos + BATCH;                               // 2048 B

  knorm_e<<<BATCH, 64, 0, stream>>>(E, En);
  klabel <<<64, 512, 0, stream>>>(En, W, labels, lcos, lphi);
  kmain  <<<GRID, 512, 0, stream>>>(En, W, psum);
  kred1  <<<NRED, 512, 0, stream>>>(psum, pp2);
  kfinal <<<1, 512, 0, stream>>>(pp2, lcos, lphi, out);
}

// Round 5
// 126.390 us; speedup vs baseline: 4.2472x; 1.2708x over previous
//
#include <hip/hip_runtime.h>
#include <hip/hip_bf16.h>
#include <math.h>

#define BATCH 512
#define EMBED 512
#define NCLS  100000
#define NTILE 1563      // 64-class tiles (last half-padded)
#define NCG   128       // column groups
#define GRID  256

typedef __attribute__((ext_vector_type(4)))  float f32x4;
typedef __attribute__((ext_vector_type(16))) float f32x16;

constexpr float kCOS_M = 0.8775825618903728f;   // cos(0.5)
constexpr float kSIN_M = 0.4794255386042030f;   // sin(0.5)
constexpr float kTHR   = -0.8775825618903728f;  // cos(pi-0.5)
constexpr float kMM    = 0.2397127693021015f;   // sin(pi-0.5)*0.5

#define BARRIER() asm volatile("s_waitcnt lgkmcnt(0)\n\ts_barrier" ::: "memory")

// ---------------- K1: normalize embeddings -> fp8 (x16), row-swizzled ----------------
// En8 row r, 8B-chunk position p holds logical k-chunk (p ^ (r&63)); kmain's
// global_load_lds then copies LINEARLY and ds_reads apply the same XOR.
__global__ void knorm_e(const float* __restrict__ E, unsigned int* __restrict__ En8) {
  int row = blockIdx.x;
  int l = threadIdx.x;                       // 64 lanes; lane owns elems 8l..8l+7
  const f32x4* src = (const f32x4*)(E + row * EMBED);
  f32x4 a = src[2 * l], b = src[2 * l + 1];
  float ss = a.x*a.x + a.y*a.y + a.z*a.z + a.w*a.w
           + b.x*b.x + b.y*b.y + b.z*b.z + b.w*b.w;
#pragma unroll
  for (int d = 1; d < 64; d <<= 1) ss += __shfl_xor(ss, d);
  float s = 16.0f / fmaxf(sqrtf(ss), 1e-12f);
  int w0 = __builtin_amdgcn_cvt_pk_fp8_f32(a.x * s, a.y * s, 0, false);
  w0     = __builtin_amdgcn_cvt_pk_fp8_f32(a.z * s, a.w * s, w0, true);
  int w1 = __builtin_amdgcn_cvt_pk_fp8_f32(b.x * s, b.y * s, 0, false);
  w1     = __builtin_amdgcn_cvt_pk_fp8_f32(b.z * s, b.w * s, w1, true);
  int pos = l ^ (row & 63);
  uint2 pk; pk.x = (unsigned)w0; pk.y = (unsigned)w1;
  *(uint2*)(&En8[row * 128 + pos * 2]) = pk;
}

// ---------------- K2: label-column cosine + margin in f32 ----------------
__global__ void klabel(const float* __restrict__ E, const float* __restrict__ W,
                       const int* __restrict__ labels,
                       float* __restrict__ lcos, float* __restrict__ lphi)
{
  int r = blockIdx.x * 8 + (threadIdx.x >> 6);
  int l = threadIdx.x & 63;
  int lbl = labels[r];
  const float* ep = E + (size_t)r * EMBED + l * 8;
  const float* wp = W + (size_t)lbl * EMBED + l * 8;
  f32x4 e0 = *(const f32x4*)ep,       e1 = *(const f32x4*)(ep + 4);
  f32x4 w0 = *(const f32x4*)wp,       w1 = *(const f32x4*)(wp + 4);
  float dot = e0.x*w0.x + e0.y*w0.y + e0.z*w0.z + e0.w*w0.w
            + e1.x*w1.x + e1.y*w1.y + e1.z*w1.z + e1.w*w1.w;
  float se = e0.x*e0.x + e0.y*e0.y + e0.z*e0.z + e0.w*e0.w
           + e1.x*e1.x + e1.y*e1.y + e1.z*e1.z + e1.w*e1.w;
  float sw = w0.x*w0.x + w0.y*w0.y + w0.z*w0.z + w0.w*w0.w
           + w1.x*w1.x + w1.y*w1.y + w1.z*w1.z + w1.w*w1.w;
#pragma unroll
  for (int d = 1; d < 64; d <<= 1) {
    dot += __shfl_xor(dot, d); se += __shfl_xor(se, d); sw += __shfl_xor(sw, d);
  }
  float cosv = dot / (fmaxf(sqrtf(se), 1e-12f) * fmaxf(sqrtf(sw), 1e-12f));
  float cc = fminf(fmaxf(cosv, -1.f), 1.f);
  float sine = sqrtf(fmaxf(1.f - cc * cc, 0.f));
  float phi = (cosv > kTHR) ? (cosv * kCOS_M - sine * kSIN_M) : (cosv - kMM);
  if (l == 0) { lcos[r] = 64.f * cosv; lphi[r] = 64.f * phi; }
}

// ---------------- K3: A-resident fp8 GEMM + fixed-max expsum ----------------
// 256 blocks = 2 panels x 128 col-groups (XCD-paired siblings). A panel
// (256 rows x 512 K fp8 = 128KB) resident in LDS; only B (16KB f32/phase)
// streams, reg-staged 2 phases deep. Barriers never drain vmcnt.
__global__ __launch_bounds__(512, 2) void kmain(
    const unsigned char* __restrict__ En8, const float* __restrict__ W,
    float* __restrict__ psum)
{
  __shared__ unsigned char Asm[256 * 512];   // 128 KB, swizzled fp8
  __shared__ unsigned char Bsm[2][4096];     // 2 x 4 KB fp8 [s8][class]
  __shared__ float rowsum[64];

  int bid = blockIdx.x;
  int xcd = bid & 7, r5 = bid >> 3;
  int panel = r5 & 1, sgrp = r5 >> 1;
  int cg = xcd + 8 * sgrp;                   // 0..127

  int tid = threadIdx.x;
  int w = tid >> 6, l = tid & 63;
  int wr = w >> 1, wc = w & 1;               // 4 row-waves x 2 col-waves
  int cl = l & 31, hi = l >> 5;
  int bcls = tid >> 3, bseg = tid & 7;       // B ownership

  int nt = (cg < 27) ? 13 : 12;              // 1563 = 12*128 + 27
  int nph = nt * 8;

  // ---- stage A: pure linear glds copy (source pre-swizzled) ----
#pragma unroll
  for (int i = 0; i < 16; ++i) {
    int base = (i * 512 + w * 64) * 16;
    __builtin_amdgcn_global_load_lds(
        (const __attribute__((address_space(1))) void*)(En8 + (size_t)panel * 131072 + base + l * 16),
        (__attribute__((address_space(3))) void*)(&Asm[base]),
        16, 0, 0);
  }

  f32x4 Ra0, Ra1, Rb0, Rb1;
  float ssqA = 0.f, ssqB = 0.f;

  auto loadB = [&](int q, f32x4& v0, f32x4& v1) {
    int ct = cg + NCG * (q >> 3);
    int cls = ct * 64 + bcls;
    if (cls >= NCLS) cls = NCLS - 1;
    const float* p = W + (size_t)cls * EMBED + (q & 7) * 64 + bseg * 8;
    v0 = *(const f32x4*)p;
    v1 = *(const f32x4*)(p + 4);
  };

  auto writeB = [&](int q, f32x4 v0, f32x4 v1) {
    float x0 = v0.x*128.f, x1 = v0.y*128.f, x2 = v0.z*128.f, x3 = v0.w*128.f;
    float x4 = v1.x*128.f, x5 = v1.y*128.f, x6 = v1.z*128.f, x7 = v1.w*128.f;
    float t = x0*x0 + x1*x1 + x2*x2 + x3*x3 + x4*x4 + x5*x5 + x6*x6 + x7*x7;
    if ((q >> 3) & 1) ssqB += t; else ssqA += t;
    int w0 = __builtin_amdgcn_cvt_pk_fp8_f32(x0, x1, 0, false);
    w0     = __builtin_amdgcn_cvt_pk_fp8_f32(x2, x3, w0, true);
    int w1 = __builtin_amdgcn_cvt_pk_fp8_f32(x4, x5, 0, false);
    w1     = __builtin_amdgcn_cvt_pk_fp8_f32(x6, x7, w1, true);
    int cidx = bcls ^ (bseg << 2);           // write swizzle (bijective per slot)
    uint2 pk; pk.x = (unsigned)w0; pk.y = (unsigned)w1;
    *(uint2*)(&Bsm[q & 1][bseg * 512 + cidx * 8]) = pk;
  };

  f32x16 acc0, acc1, S0, S1;
#pragma unroll
  for (int e = 0; e < 16; ++e) { acc0[e] = 0.f; acc1[e] = 0.f; S0[e] = 0.f; S1[e] = 0.f; }

  const unsigned char* A0 = Asm + (wr * 64 + cl) * 512;
  const unsigned char* A1 = A0 + 32 * 512;
  int rm0 = cl, rm1 = 32 | cl;

  auto compute = [&](int p) {
    int buf = p & 1, t = p & 7;
#pragma unroll
    for (int kk = 0; kk < 4; ++kk) {
      int s8b = kk * 2 + hi;
      int s8 = t * 8 + s8b;
      long a0 = *(const long*)(A0 + ((s8 ^ rm0) << 3));
      long a1 = *(const long*)(A1 + ((s8 ^ rm1) << 3));
      int cidx = (wc * 32 + cl) ^ (s8b << 2);
      long bb = *(const long*)(&Bsm[buf][s8b * 512 + cidx * 8]);
      acc0 = __builtin_amdgcn_mfma_f32_32x32x16_fp8_fp8(a0, bb, acc0, 0, 0, 0);
      acc1 = __builtin_amdgcn_mfma_f32_32x32x16_fp8_fp8(a1, bb, acc1, 0, 0, 0);
    }
  };

  // ---- prologue ----
  loadB(0, Ra0, Ra1);
  loadB(1, Rb0, Rb1);
  writeB(0, Ra0, Ra1);
  loadB(2, Ra0, Ra1);
  writeB(1, Rb0, Rb1);
  loadB(3, Rb0, Rb1);
  asm volatile("s_waitcnt vmcnt(0)" ::: "memory");   // one-time: A + Bbuf0/1 ready
  BARRIER();

  for (int p = 0; p < nph; p += 2) {
    // -------- even phase --------
    compute(p);
    BARRIER();                                  // readers done with Bsm[0]
    if (p + 2 < nph) writeB(p + 2, Ra0, Ra1);
    if (p + 4 < nph) loadB(p + 4, Ra0, Ra1);
    BARRIER();                                  // Bsm[0] (for p+2) visible
    // -------- odd phase --------
    compute(p + 1);
    BARRIER();
    if (p + 3 < nph) writeB(p + 3, Rb0, Rb1);
    if (p + 5 < nph) loadB(p + 5, Rb0, Rb1);
    bool boundary = ((p + 1) & 7) == 7;
    int t_idx = (p + 1) >> 3;
    if (boundary) {
      float sq = (t_idx & 1) ? ssqB : ssqA;
      sq += __shfl_xor(sq, 1); sq += __shfl_xor(sq, 2); sq += __shfl_xor(sq, 4);
      if (bseg == 0) rowsum[bcls] = sq;
      if (t_idx & 1) ssqB = 0.f; else ssqA = 0.f;
    }
    BARRIER();
    if (boundary) {
      float rs = rowsum[wc * 32 + cl];
      float rn = 4.0f / fmaxf(sqrtf(rs), 1e-30f);
      int cls = (cg + NCG * t_idx) * 64 + wc * 32 + cl;
      float vmask = (cls < NCLS) ? 1.0f : 0.0f;
#pragma unroll
      for (int e = 0; e < 16; ++e) {
        float v0 = vmask * __expf(fmaf(acc0[e], rn, -64.0f));
        float v1 = vmask * __expf(fmaf(acc1[e], rn, -64.0f));
        v0 += __shfl_xor(v0, 1); v0 += __shfl_xor(v0, 2); v0 += __shfl_xor(v0, 4);
        v0 += __shfl_xor(v0, 8); v0 += __shfl_xor(v0, 16);
        v1 += __shfl_xor(v1, 1); v1 += __shfl_xor(v1, 2); v1 += __shfl_xor(v1, 4);
        v1 += __shfl_xor(v1, 8); v1 += __shfl_xor(v1, 16);
        S0[e] += v0; S1[e] += v1;
        acc0[e] = 0.f; acc1[e] = 0.f;
      }
    }
  }

  // ---- final store: per-wave per-row partial sums ----
  if ((l & 31) == 0) {
#pragma unroll
    for (int e = 0; e < 16; ++e) {
      int rmap = (e & 3) + 8 * (e >> 2) + 4 * hi;
      psum[bid * 512 + wc * 256 + wr * 64 + rmap]      = S0[e];
      psum[bid * 512 + wc * 256 + wr * 64 + 32 + rmap] = S1[e];
    }
  }
}

// ---------------- K4: reduce psum over the 8 XCD-copies per group ----------------
__global__ void kred1(const float* __restrict__ psum, float* __restrict__ pp2) {
  int g = blockIdx.x, tid = threadIdx.x;   // 32 x 256; group g = bids 8g..8g+7 (same panel g&1)
  float s = 0.f;
#pragma unroll
  for (int x = 0; x < 8; ++x) {
    const float* base = psum + (size_t)(g * 8 + x) * 512;
    s += base[tid] + base[256 + tid];
  }
  pp2[g * 256 + tid] = s;
}

// ---------------- K5: final combine + label adjust + NLL mean ----------------
__global__ void kfinal(const float* __restrict__ pp2, const float* __restrict__ lcos,
                       const float* __restrict__ lphi, float* __restrict__ out)
{
  int gr = threadIdx.x;                    // 512 rows
  int panel = gr >> 8, prow = gr & 255;
  float S = 0.f;
#pragma unroll
  for (int g = 0; g < 16; ++g) S += pp2[(2 * g + panel) * 256 + prow];
  float lc = lcos[gr], lp = lphi[gr];
  S = S - __expf(lc - 64.f) + __expf(lp - 64.f);
  float nll = 64.f + __logf(S) - lp;
#pragma unroll
  for (int d = 1; d < 64; d <<= 1) nll += __shfl_xor(nll, d);
  __shared__ float sm[8];
  if ((gr & 63) == 0) sm[gr >> 6] = nll;
  __syncthreads();
  if (gr == 0) {
    float t = 0.f;
    for (int k = 0; k < 8; ++k) t += sm[k];
    out[0] = t * (1.0f / 512.0f);
  }
}

extern "C" void kernel_launch(void* const* d_in, const int* in_sizes, int n_in,
                              void* d_out, int out_size, void* d_ws, size_t ws_size,
                              hipStream_t stream)
{
  const float* E      = (const float*)d_in[0];
  const int*   labels = (const int*)d_in[1];
  const float* W      = (const float*)d_in[2];
  float* out = (float*)d_out;

  char* ws = (char*)d_ws;
  unsigned int* En8 = (unsigned int*)ws;                       // 512*512 fp8 = 262144 B
  float* psum = (float*)(ws + 262144);                         // 256*512*4 = 524288 B
  float* pp2  = (float*)(ws + 262144 + 524288);                // 32*256*4 = 32768 B
  float* lcos = (float*)(ws + 262144 + 524288 + 32768);        // 2048 B
  float* lphi = lcos + BATCH;                                  // 2048 B

  knorm_e<<<BATCH, 64, 0, stream>>>(E, En8);
  klabel <<<64, 512, 0, stream>>>(E, W, labels, lcos, lphi);
  kmain  <<<GRID, 512, 0, stream>>>((const unsigned char*)En8, W, psum);
  kred1  <<<32, 256, 0, stream>>>(psum, pp2);
  kfinal <<<1, 512, 0, stream>>>(pp2, lcos, lphi, out);
}

// Round 6
// 89.125 us; speedup vs baseline: 6.0230x; 1.4181x over previous
//
#include <hip/hip_runtime.h>
#include <hip/hip_bf16.h>
#include <math.h>

#define BATCH 512
#define EMBED 512
#define NCLS  100000
#define NCG   128          // class column-groups (64 classes each per tile row)
#define NBLK  512          // kmain grid: 4 panels x 128 cgs

typedef __attribute__((ext_vector_type(4)))  float f32x4;
typedef __attribute__((ext_vector_type(16))) float f32x16;
typedef __attribute__((ext_vector_type(2)))  long  i64x2;

constexpr float kCOS_M = 0.8775825618903728f;   // cos(0.5)
constexpr float kSIN_M = 0.4794255386042030f;   // sin(0.5)
constexpr float kTHR   = -0.8775825618903728f;  // cos(pi-0.5)
constexpr float kMM    = 0.2397127693021015f;   // sin(pi-0.5)*0.5

#define BARRIER() asm volatile("s_waitcnt lgkmcnt(0)\n\ts_barrier" ::: "memory")

// ---------------- K1: normalize embeddings -> fp8 x16, hi-split + XOR-swizzled ----
// Lane l owns elements k = 8l..8l+7  (k16 = l>>1, hi = l&1, => slot = (l&1)*16 + (l>>2),
// half = (l>>1)&1).  Physical 16B-slot s of row r holds logical slot s ^ (r&31).
__global__ void knorm_e(const float* __restrict__ E, unsigned char* __restrict__ En8) {
  int r = blockIdx.x;
  int l = threadIdx.x;                       // 64 lanes
  const f32x4* src = (const f32x4*)(E + r * EMBED);
  f32x4 a = src[2 * l], b = src[2 * l + 1];
  float ss = a.x*a.x + a.y*a.y + a.z*a.z + a.w*a.w
           + b.x*b.x + b.y*b.y + b.z*b.z + b.w*b.w;
#pragma unroll
  for (int d = 1; d < 64; d <<= 1) ss += __shfl_xor(ss, d);
  float s = 16.0f / fmaxf(sqrtf(ss), 1e-12f);
  int w0 = __builtin_amdgcn_cvt_pk_fp8_f32(a.x * s, a.y * s, 0, false);
  w0     = __builtin_amdgcn_cvt_pk_fp8_f32(a.z * s, a.w * s, w0, true);
  int w1 = __builtin_amdgcn_cvt_pk_fp8_f32(b.x * s, b.y * s, 0, false);
  w1     = __builtin_amdgcn_cvt_pk_fp8_f32(b.z * s, b.w * s, w1, true);
  int slotL = (l & 1) * 16 + (l >> 2);
  int half  = (l >> 1) & 1;
  uint2 pk; pk.x = (unsigned)w0; pk.y = (unsigned)w1;
  *(uint2*)(En8 + r * 512 + (((slotL ^ (r & 31)) << 4) | (half << 3))) = pk;
}

// ---------------- K2: label-column cosine + margin in f32 ----------------
__global__ void klabel(const float* __restrict__ E, const float* __restrict__ W,
                       const int* __restrict__ labels,
                       float* __restrict__ lcos, float* __restrict__ lphi)
{
  int r = blockIdx.x * 8 + (threadIdx.x >> 6);
  int l = threadIdx.x & 63;
  int lbl = labels[r];
  const float* ep = E + (size_t)r * EMBED + l * 8;
  const float* wp = W + (size_t)lbl * EMBED + l * 8;
  f32x4 e0 = *(const f32x4*)ep, e1 = *(const f32x4*)(ep + 4);
  f32x4 w0 = *(const f32x4*)wp, w1 = *(const f32x4*)(wp + 4);
  float dot = e0.x*w0.x + e0.y*w0.y + e0.z*w0.z + e0.w*w0.w
            + e1.x*w1.x + e1.y*w1.y + e1.z*w1.z + e1.w*w1.w;
  float se = e0.x*e0.x + e0.y*e0.y + e0.z*e0.z + e0.w*e0.w
           + e1.x*e1.x + e1.y*e1.y + e1.z*e1.z + e1.w*e1.w;
  float sw = w0.x*w0.x + w0.y*w0.y + w0.z*w0.z + w0.w*w0.w
           + w1.x*w1.x + w1.y*w1.y + w1.z*w1.z + w1.w*w1.w;
#pragma unroll
  for (int d = 1; d < 64; d <<= 1) {
    dot += __shfl_xor(dot, d); se += __shfl_xor(se, d); sw += __shfl_xor(sw, d);
  }
  float cosv = dot / (fmaxf(sqrtf(se), 1e-12f) * fmaxf(sqrtf(sw), 1e-12f));
  float cc = fminf(fmaxf(cosv, -1.f), 1.f);
  float sine = sqrtf(fmaxf(1.f - cc * cc, 0.f));
  float phi = (cosv > kTHR) ? (cosv * kCOS_M - sine * kSIN_M) : (cosv - kMM);
  if (l == 0) { lcos[r] = 64.f * cosv; lphi[r] = 64.f * phi; }
}

// ---------------- K3: fused fp8 GEMM + fixed-max expsum ----------------
// 512 blocks (2/CU) = 4 panels x 128 cgs, XCD-paired so sibling panels share L2.
// A panel (128 x 512 fp8 = 64KB) LDS-resident; B (16KB f32/phase) reg-staged
// 2 phases deep -> cvt fp8 -> ds_write. ONE barrier per phase, zero vmcnt waits.
__global__ __launch_bounds__(512, 4) void kmain(
    const unsigned char* __restrict__ En8, const float* __restrict__ W,
    float* __restrict__ psum)
{
  __shared__ unsigned char Asm[128 * 512];   // 64 KB
  __shared__ unsigned char Bsm[2][4096];     // 2 x 4 KB
  __shared__ float rowsum[64];
  __shared__ float smemS[2][128];

  int bid = blockIdx.x;
  int xcd = bid & 7;
  int panel = (bid >> 3) & 3;
  int grp = bid >> 5;                        // 0..15
  int cg = xcd | (grp << 3);                 // 0..127

  int tid = threadIdx.x;
  int w = tid >> 6, l = tid & 63;
  int wr = w >> 1, wc = w & 1;               // 4 row-waves x 2 col-waves
  int cl = l & 31, hi = l >> 5;
  int bcls = tid >> 3, bseg = tid & 7;       // B staging ownership

  int nt = (cg < 27) ? 13 : 12;              // 1563 = 12*128 + 27
  int nph = nt * 8;

  // ---- stage A panel: pure linear glds (source pre-swizzled by knorm_e) ----
#pragma unroll
  for (int i = 0; i < 8; ++i) {
    int base = i * 8192 + w * 1024;
    __builtin_amdgcn_global_load_lds(
        (const __attribute__((address_space(1))) void*)(En8 + panel * 65536 + base + l * 16),
        (__attribute__((address_space(3))) void*)(&Asm[base]), 16, 0, 0);
  }

  f32x4 Ra0, Ra1, Rb0, Rb1;
  float ssq = 0.f;
  const int bregion = (bseg & 1) * 2 + (bseg >> 2);   // [hi*2 + k16pair]
  const int bhalf = (bseg >> 1) & 1;

  auto loadB = [&](int q, f32x4& v0, f32x4& v1) {
    int T = q >> 3;
    int cls = (cg + (T << 7)) * 64 + bcls;
    if (cls >= NCLS) cls = NCLS - 1;
    const float* p = W + (size_t)cls * EMBED + (q & 7) * 64 + bseg * 8;
    v0 = *(const f32x4*)p;
    v1 = *(const f32x4*)(p + 4);
  };

  auto writeB = [&](int buf, f32x4 v0, f32x4 v1) {
    float x0 = v0.x*128.f, x1 = v0.y*128.f, x2 = v0.z*128.f, x3 = v0.w*128.f;
    float x4 = v1.x*128.f, x5 = v1.y*128.f, x6 = v1.z*128.f, x7 = v1.w*128.f;
    ssq += x0*x0 + x1*x1 + x2*x2 + x3*x3 + x4*x4 + x5*x5 + x6*x6 + x7*x7;
    int w0 = __builtin_amdgcn_cvt_pk_fp8_f32(x0, x1, 0, false);
    w0     = __builtin_amdgcn_cvt_pk_fp8_f32(x2, x3, w0, true);
    int w1 = __builtin_amdgcn_cvt_pk_fp8_f32(x4, x5, 0, false);
    w1     = __builtin_amdgcn_cvt_pk_fp8_f32(x6, x7, w1, true);
    uint2 pk; pk.x = (unsigned)w0; pk.y = (unsigned)w1;
    *(uint2*)(&Bsm[buf][bregion * 1024 + bcls * 16 + bhalf * 8]) = pk;
  };

  f32x16 acc, S;
#pragma unroll
  for (int e = 0; e < 16; ++e) { acc[e] = 0.f; S[e] = 0.f; }

  const unsigned char* Abase = &Asm[(wr * 32 + cl) * 512];
  const int arowx = cl;                       // (wr*32+cl)&31 == cl
  const unsigned char* Bcol0 = &Bsm[0][(hi * 2) * 1024 + (wc * 32 + cl) * 16];
  const unsigned char* Bcol1 = &Bsm[1][(hi * 2) * 1024 + (wc * 32 + cl) * 16];

  auto compute = [&](const unsigned char* bb, int pt) {
    int t0 = pt * 2;
    i64x2 a0 = *(const i64x2*)(Abase + ((((hi << 4) | t0)       ^ arowx) << 4));
    i64x2 a1 = *(const i64x2*)(Abase + ((((hi << 4) | (t0 + 1)) ^ arowx) << 4));
    i64x2 b0 = *(const i64x2*)(bb);
    i64x2 b1 = *(const i64x2*)(bb + 1024);
    acc = __builtin_amdgcn_mfma_f32_32x32x16_fp8_fp8(a0[0], b0[0], acc, 0, 0, 0);
    acc = __builtin_amdgcn_mfma_f32_32x32x16_fp8_fp8(a0[1], b0[1], acc, 0, 0, 0);
    acc = __builtin_amdgcn_mfma_f32_32x32x16_fp8_fp8(a1[0], b1[0], acc, 0, 0, 0);
    acc = __builtin_amdgcn_mfma_f32_32x32x16_fp8_fp8(a1[1], b1[1], acc, 0, 0, 0);
  };

  auto ssqred = [&]() {
    float sq = ssq;
    sq += __shfl_xor(sq, 1); sq += __shfl_xor(sq, 2); sq += __shfl_xor(sq, 4);
    if (bseg == 0) rowsum[bcls] = sq;
    ssq = 0.f;
  };

  auto epilogue = [&](int T) {
    float rs = fmaxf(rowsum[wc * 32 + cl], 1e-30f);
    float rn = 4.0f / sqrtf(rs);
    int colg = (cg + (T << 7)) * 64 + wc * 32 + cl;
    float vm = (colg < NCLS) ? 1.0f : 0.0f;
#pragma unroll
    for (int e = 0; e < 16; ++e) {
      float v = __expf(fmaf(acc[e], rn, -64.0f));
      S[e] = fmaf(v, vm, S[e]);
      acc[e] = 0.f;
    }
  };

  // ---- prologue: tile 0 fully staged, tiles' chunks 2,3 in regs ----
  loadB(0, Ra0, Ra1); loadB(1, Rb0, Rb1);
  writeB(0, Ra0, Ra1); writeB(1, Rb0, Rb1);
  loadB(2, Ra0, Ra1); loadB(3, Rb0, Rb1);
  asm volatile("s_waitcnt vmcnt(0)" ::: "memory");
  BARRIER();

  for (int p = 0; p < nph; p += 2) {
    // ---- even phase ----
    compute(Bcol0, p & 7);
    BARRIER();
    if (p + 2 < nph) writeB(0, Ra0, Ra1);
    if (p + 4 < nph) loadB(p + 4, Ra0, Ra1);
    // ---- odd phase ----
    int po = p + 1;
    compute(Bcol1, po & 7);
    if ((po & 7) == 7) epilogue(po >> 3);
    BARRIER();
    if (po + 2 < nph) writeB(1, Rb0, Rb1);
    if (po + 4 < nph) loadB(po + 4, Rb0, Rb1);
    if (((po + 2) & 7) == 7) ssqred();        // last chunk of a tile just staged
  }

  // ---- final: reduce S across the 32 col-lanes, combine col-waves ----
#pragma unroll
  for (int e = 0; e < 16; ++e) {
    float v = S[e];
    v += __shfl_xor(v, 1); v += __shfl_xor(v, 2); v += __shfl_xor(v, 4);
    v += __shfl_xor(v, 8); v += __shfl_xor(v, 16);
    S[e] = v;
  }
  __syncthreads();
  if (cl == 0) {
#pragma unroll
    for (int e = 0; e < 16; ++e) {
      int row = wr * 32 + (e & 3) + 8 * (e >> 2) + 4 * hi;
      smemS[wc][row] = S[e];
    }
  }
  __syncthreads();
  if (tid < 128) psum[bid * 128 + tid] = smemS[0][tid] + smemS[1][tid];
}

// ---------------- K4: reduce over the 8 XCD siblings of each (panel,grp) ----
__global__ void kred1(const float* __restrict__ psum, float* __restrict__ pp2) {
  int g = blockIdx.x;            // 0..63: panel = g>>4, grp = g&15
  int r = threadIdx.x;           // 128
  int panel = g >> 4, grp = g & 15;
  float s = 0.f;
#pragma unroll
  for (int x = 0; x < 8; ++x) {
    int bid = x | (panel << 3) | (grp << 5);
    s += psum[bid * 128 + r];
  }
  pp2[g * 128 + r] = s;
}

// ---------------- K5: final combine + label adjust + NLL mean ----------------
__global__ void kfinal(const float* __restrict__ pp2, const float* __restrict__ lcos,
                       const float* __restrict__ lphi, float* __restrict__ out)
{
  int tid = threadIdx.x;         // 512 = one thread per batch row
  int panel = tid >> 7, rl = tid & 127;
  float S = 0.f;
#pragma unroll
  for (int grp = 0; grp < 16; ++grp)
    S += pp2[((panel << 4) | grp) * 128 + rl];
  float lc = lcos[tid], lp = lphi[tid];
  S = S - __expf(lc - 64.f) + __expf(lp - 64.f);
  float nll = 64.f + __logf(S) - lp;
#pragma unroll
  for (int d = 1; d < 64; d <<= 1) nll += __shfl_xor(nll, d);
  __shared__ float sm[8];
  if ((tid & 63) == 0) sm[tid >> 6] = nll;
  __syncthreads();
  if (tid == 0) {
    float t = 0.f;
    for (int k = 0; k < 8; ++k) t += sm[k];
    out[0] = t * (1.0f / 512.0f);
  }
}

extern "C" void kernel_launch(void* const* d_in, const int* in_sizes, int n_in,
                              void* d_out, int out_size, void* d_ws, size_t ws_size,
                              hipStream_t stream)
{
  const float* E      = (const float*)d_in[0];
  const int*   labels = (const int*)d_in[1];
  const float* W      = (const float*)d_in[2];
  float* out = (float*)d_out;

  char* ws = (char*)d_ws;
  unsigned char* En8 = (unsigned char*)ws;              // 512*512 = 262144 B
  float* psum = (float*)(ws + 262144);                  // 512*128*4 = 262144 B
  float* pp2  = (float*)(ws + 524288);                  // 64*128*4 = 32768 B
  float* lcos = (float*)(ws + 557056);                  // 2048 B
  float* lphi = lcos + BATCH;                           // 2048 B

  knorm_e<<<BATCH, 64, 0, stream>>>(E, En8);
  klabel <<<64, 512, 0, stream>>>(E, W, labels, lcos, lphi);
  kmain  <<<NBLK, 512, 0, stream>>>(En8, W, psum);
  kred1  <<<64, 128, 0, stream>>>(psum, pp2);
  kfinal <<<1, 512, 0, stream>>>(pp2, lcos, lphi, out);
}